// Round 1
// baseline (76.751 us; speedup 1.0000x reference)
//
#include <hip/hip_runtime.h>

// MCPBRNN_SW_Constant_Routing — outputs only need the scan pre-state at each
// row's last column. f = 1 - sigmoid(w) <= 0.5, so f^m < 3e-39 at m=128:
// truncate the infinite scan history to the 128 preceding elements (all in
// the same x row). One wave (64 lanes) per output row, 2 terms/lane.

#define B_DIM 4096
#define T_DIM 2048

__global__ __launch_bounds__(256) void mcpbrnn_routing_kernel(
    const float* __restrict__ x,
    const float* __restrict__ weight_r_yom,
    const int* __restrict__ time_lag_p,
    float* __restrict__ out)
{
    const int tid  = blockIdx.x * blockDim.x + threadIdx.x;
    const int row  = tid >> 6;   // one wave per output row g in [0, B)
    const int lane = tid & 63;
    if (row >= B_DIM) return;

    const int time_lag = time_lag_p[0];

    const float oo = 1.0f / (1.0f + expf(-weight_r_yom[0]));
    const float f  = 1.0f - oo;

    float* __restrict__ h_n  = out;               // (B,1)
    float* __restrict__ c_n  = out + B_DIM;       // (B,1)
    float* __restrict__ g_oo = out + 2 * B_DIM;   // (B,1)
    float* __restrict__ g_f  = out + 3 * B_DIM;   // (B,1)

    if (row < time_lag) {
        // untouched rows: all four outputs are 0 (d_out is poisoned 0xAA)
        if (lane == 0) {
            h_n[row]  = 0.0f;
            c_n[row]  = 0.0f;
            g_oo[row] = 0.0f;
            g_f[row]  = 0.0f;
        }
        return;
    }

    // c_last for logical row r = row - time_lag:
    //   c = sum_{m=0}^{127} f^m * u[idx-1-m],  idx = r*T + (T-1),
    //   u[j] = x.flat[time_lag*T + j]  =>  u[idx-1-m] = x.flat[row*T + T-2 - m]
    const long long base = (long long)row * T_DIM + (T_DIM - 2);

    // f^lane via 6-bit repeated squaring (exact weight per lane)
    float p  = f;     // f^(2^b)
    float wl = 1.0f;  // f^lane
    int bits = lane;
    #pragma unroll
    for (int b = 0; b < 6; ++b) {
        if (bits & 1) wl *= p;
        p *= p;
        bits >>= 1;
    }
    const float f64 = p;  // f^64

    float s = wl * x[base - lane] + (wl * f64) * x[base - 64 - lane];

    // 64-lane butterfly reduction
    #pragma unroll
    for (int off = 32; off >= 1; off >>= 1)
        s += __shfl_xor(s, off, 64);

    if (lane == 0) {
        c_n[row]  = s;
        h_n[row]  = oo * s;
        g_oo[row] = oo;
        g_f[row]  = f;
    }
}

extern "C" void kernel_launch(void* const* d_in, const int* in_sizes, int n_in,
                              void* d_out, int out_size, void* d_ws, size_t ws_size,
                              hipStream_t stream)
{
    const float* x  = (const float*)d_in[0];
    const float* w  = (const float*)d_in[1];
    // d_in[2] = y_obs (unused), d_in[3] = epoch (unused)
    const int* tlag = (const int*)d_in[4];

    float* out = (float*)d_out;

    // 4096 waves (one per row), 4 waves per 256-thread block
    const int blocks = (B_DIM * 64) / 256;  // 1024
    mcpbrnn_routing_kernel<<<blocks, 256, 0, stream>>>(x, w, tlag, out);
}